// Round 1
// baseline (551.494 us; speedup 1.0000x reference)
//
#include <hip/hip_runtime.h>

#define H  400
#define NB 16
#define CI 4
#define CO 32

// ---------------- K1: transpose each 400x400 plane of X into XT ----------------
__global__ __launch_bounds__(256) void k_transpose(const float* __restrict__ x,
                                                   float* __restrict__ xt) {
    __shared__ float tile[50][51];
    int b = blockIdx.x;
    int tj = b & 7;
    int ti = (b >> 3) & 7;
    int nc = b >> 6;               // 0..63 = n*4+c
    const float* src = x + (size_t)nc * H * H;
    float* dst = xt + (size_t)nc * H * H;
    int i0 = ti * 50, j0 = tj * 50;
    for (int e = threadIdx.x; e < 2500; e += 256) {
        int r = e / 50, c = e % 50;
        tile[r][c] = src[(i0 + r) * H + j0 + c];
    }
    __syncthreads();
    for (int e = threadIdx.x; e < 2500; e += 256) {
        int r = e / 50, c = e % 50;
        dst[(j0 + r) * H + i0 + c] = tile[c][r];
    }
}

// ---------------- K2: rows[n,o,m] and cols[n,o,m] ----------------
// rows[n,o,m] = sum_{c,k} X[n,c,m,k]*T[o,c,m,k]
// cols[n,o,m] = sum_{c,k} X[n,c,k,m]*T[o,c,m,k]   (T symmetric in (i,j))
// One block per m. T-row rebuilt from L on the fly in LDS.
#define KC 40
__global__ __launch_bounds__(256) void k_rowscols(const float* __restrict__ x,
        const float* __restrict__ xcol, int xt_flag, const float* __restrict__ L,
        float* __restrict__ rows, float* __restrict__ cols)
{
    __shared__ __align__(16) float Lm[CO * CI * 4];   // L[o,c,m,:]
    __shared__ __align__(16) float Xr[NB * CI * KC];  // X[n,c,m,k0+k]
    __shared__ __align__(16) float Xc[NB * CI * KC];  // X[n,c,k0+k,m]
    __shared__ __align__(16) float Tr[CO * 164];      // o*164 + c*KC + k (pad for banks)
    int m = blockIdx.x;
    int tid = threadIdx.x;
    const float4* L4 = (const float4*)L;
    if (tid < CO * CI) ((float4*)Lm)[tid] = L4[tid * H + m];

    int o  = tid & 31;
    int n0 = tid >> 5;     // 0..7
    int n1 = n0 + 8;
    float ar0 = 0.f, ar1 = 0.f, ac0 = 0.f, ac1 = 0.f;

    for (int ch = 0; ch < H / KC; ++ch) {
        int k0 = ch * KC;
        __syncthreads();
        for (int e = tid; e < NB * CI * KC; e += 256) {
            int k = e % KC;
            int nc = e / KC;
            Xr[e] = x[(nc * H + m) * H + k0 + k];
            Xc[e] = xt_flag ? xcol[(nc * H + m) * H + k0 + k]
                            : xcol[(nc * H + k0 + k) * H + m];
        }
        for (int e = tid; e < CO * CI * KC; e += 256) {
            int k = e % KC;
            int oc = e / KC;                       // o*4+c
            float4 lv = L4[oc * H + k0 + k];
            float4 lm = ((const float4*)Lm)[oc];
            Tr[(oc >> 2) * 164 + (oc & 3) * KC + k] =
                lv.x * lm.x + lv.y * lm.y + lv.z * lm.z + lv.w * lm.w;
        }
        __syncthreads();
        #pragma unroll
        for (int c = 0; c < CI; ++c) {
            const float4* trp = (const float4*)(Tr + o * 164 + c * KC);
            const float4* pr0 = (const float4*)(Xr + (n0 * CI + c) * KC);
            const float4* pr1 = (const float4*)(Xr + (n1 * CI + c) * KC);
            const float4* pc0 = (const float4*)(Xc + (n0 * CI + c) * KC);
            const float4* pc1 = (const float4*)(Xc + (n1 * CI + c) * KC);
            #pragma unroll
            for (int q = 0; q < KC / 4; ++q) {
                float4 tv = trp[q];
                float4 a  = pr0[q];
                float4 bb = pr1[q];
                float4 cc = pc0[q];
                float4 dd = pc1[q];
                ar0 += tv.x * a.x  + tv.y * a.y  + tv.z * a.z  + tv.w * a.w;
                ar1 += tv.x * bb.x + tv.y * bb.y + tv.z * bb.z + tv.w * bb.w;
                ac0 += tv.x * cc.x + tv.y * cc.y + tv.z * cc.z + tv.w * cc.w;
                ac1 += tv.x * dd.x + tv.y * dd.y + tv.z * dd.z + tv.w * dd.w;
            }
        }
    }
    rows[(n0 * CO + o) * H + m] = ar0;
    rows[(n1 * CO + o) * H + m] = ar1;
    cols[(n0 * CO + o) * H + m] = ac0;
    cols[(n1 * CO + o) * H + m] = ac1;
}

// ---------------- K3: final output ----------------
// 16x16 spatial tile, o-set of 8, all 16 n looped with X tile in LDS.
// Thread owns (o, ii, j-quad); its 16 T values live in registers.
#define TS 16
__global__ __launch_bounds__(512) void k_out(const float* __restrict__ x,
        const float* __restrict__ L, const float* __restrict__ bias,
        const float* __restrict__ rows, const float* __restrict__ cols,
        float* __restrict__ out)
{
    __shared__ __align__(16) float Xl[NB * CI * TS * TS];  // 64 KB [n][c][ii][jj]
    __shared__ __align__(16) float rT[NB * 8 * TS];        // 8 KB  [n][o][ii]
    __shared__ __align__(16) float cT[NB * 8 * TS];        // 8 KB  [n][o][jj]
    int b = blockIdx.x;
    int os = b / 625;              // 0..3
    int t  = b % 625;
    int ti = t / 25, tj = t % 25;
    int i0 = ti * TS, j0 = tj * TS, ob = os * 8;
    int tid = threadIdx.x;

    for (int e = tid; e < NB * 8 * TS; e += 512) {
        int ii = e & 15;
        int o  = (e >> 4) & 7;
        int n  = e >> 7;
        rT[e] = rows[(n * CO + ob + o) * H + i0 + ii];
        cT[e] = cols[(n * CO + ob + o) * H + j0 + ii];
    }
    const float4* x4 = (const float4*)x;
    float4* Xl4 = (float4*)Xl;
    for (int e = tid; e < NB * CI * TS * 4; e += 512) {
        int q  = e & 3;
        int ii = (e >> 2) & 15;
        int nc = e >> 6;
        Xl4[e] = x4[(nc * H + i0 + ii) * 100 + tj * 4 + q];
    }

    int o  = tid >> 6;             // 0..7
    int u  = tid & 63;
    int ii = u >> 2, jq = u & 3;   // jj = jq*4 .. jq*4+3
    int og = ob + o;
    const float4* L4 = (const float4*)L;
    float4 T4[CI];
    #pragma unroll
    for (int c = 0; c < CI; ++c) {
        float4 Li = L4[(og * CI + c) * H + i0 + ii];
        float4 La = L4[(og * CI + c) * H + j0 + jq * 4 + 0];
        float4 Lb = L4[(og * CI + c) * H + j0 + jq * 4 + 1];
        float4 Lc = L4[(og * CI + c) * H + j0 + jq * 4 + 2];
        float4 Ld = L4[(og * CI + c) * H + j0 + jq * 4 + 3];
        T4[c].x = Li.x * La.x + Li.y * La.y + Li.z * La.z + Li.w * La.w;
        T4[c].y = Li.x * Lb.x + Li.y * Lb.y + Li.z * Lb.z + Li.w * Lb.w;
        T4[c].z = Li.x * Lc.x + Li.y * Lc.y + Li.z * Lc.z + Li.w * Lc.w;
        T4[c].w = Li.x * Ld.x + Li.y * Ld.y + Li.z * Ld.z + Li.w * Ld.w;
    }
    float bo = bias[og];
    __syncthreads();

    const float4* cT4 = (const float4*)cT;
    float4* out4 = (float4*)out;
    for (int n = 0; n < NB; ++n) {
        float ra = rT[(n * 8 + o) * TS + ii] + bo;
        float4 ca = cT4[(n * 8 + o) * 4 + jq];
        float4 acc;
        acc.x = ra + ca.x; acc.y = ra + ca.y; acc.z = ra + ca.z; acc.w = ra + ca.w;
        #pragma unroll
        for (int c = 0; c < CI; ++c) {
            float4 xv = Xl4[((n * CI + c) * TS + ii) * 4 + jq];
            acc.x -= xv.x * T4[c].x;
            acc.y -= xv.y * T4[c].y;
            acc.z -= xv.z * T4[c].z;
            acc.w -= xv.w * T4[c].w;
        }
        out4[((n * CO + og) * H + i0 + ii) * 100 + tj * 4 + jq] = acc;
    }
}

extern "C" void kernel_launch(void* const* d_in, const int* in_sizes, int n_in,
                              void* d_out, int out_size, void* d_ws, size_t ws_size,
                              hipStream_t stream) {
    const float* x    = (const float*)d_in[0];
    const float* L    = (const float*)d_in[1];
    const float* bias = (const float*)d_in[2];
    float* out = (float*)d_out;
    char* ws = (char*)d_ws;

    size_t xt_bytes = (size_t)NB * CI * H * H * sizeof(float);   // 40,960,000
    size_t rc_elems = (size_t)NB * CO * H;                       // 204,800
    size_t rc_bytes = rc_elems * sizeof(float);

    int use_xt = (ws_size >= xt_bytes + 2 * rc_bytes);
    float* XT;
    float* rows;
    float* cols;
    if (use_xt) {
        XT   = (float*)ws;
        rows = (float*)(ws + xt_bytes);
        cols = rows + rc_elems;
    } else {
        XT   = nullptr;
        rows = (float*)ws;
        cols = rows + rc_elems;
    }

    if (use_xt) {
        k_transpose<<<4096, 256, 0, stream>>>(x, XT);
        k_rowscols<<<H, 256, 0, stream>>>(x, XT, 1, L, rows, cols);
    } else {
        k_rowscols<<<H, 256, 0, stream>>>(x, x, 0, L, rows, cols);
    }
    k_out<<<2500, 512, 0, stream>>>(x, L, bias, rows, cols, out);
}

// Round 2
// 509.242 us; speedup vs baseline: 1.0830x; 1.0830x over previous
//
#include <hip/hip_runtime.h>

#define H  400
#define NB 16
#define CI 4
#define CO 32

// ---------------- K1: transpose each 400x400 plane of X into XT ----------------
// 80x80 tiles, float4 global loads AND stores. 64 nc-planes * 25 tiles = 1600 blocks.
#define TT 80
__global__ __launch_bounds__(256) void k_transpose(const float* __restrict__ x,
                                                   float* __restrict__ xt) {
    __shared__ float tile[TT][TT + 5];   // pad 85: store-phase stride 4*85%32=21 (coprime w/ 32)
    int b = blockIdx.x;
    int tj = b % 5;
    int ti = (b / 5) % 5;
    int nc = b / 25;
    const float* src = x + (size_t)nc * H * H;
    float* dst = xt + (size_t)nc * H * H;
    int i0 = ti * TT, j0 = tj * TT;
    for (int e = threadIdx.x; e < TT * 20; e += 256) {
        int r = e / 20, q = e % 20;
        float4 v = ((const float4*)(src + (size_t)(i0 + r) * H + j0))[q];
        tile[r][q * 4 + 0] = v.x; tile[r][q * 4 + 1] = v.y;
        tile[r][q * 4 + 2] = v.z; tile[r][q * 4 + 3] = v.w;
    }
    __syncthreads();
    for (int e = threadIdx.x; e < TT * 20; e += 256) {
        int r = e / 20, q = e % 20;
        float4 v;
        v.x = tile[q * 4 + 0][r]; v.y = tile[q * 4 + 1][r];
        v.z = tile[q * 4 + 2][r]; v.w = tile[q * 4 + 3][r];
        ((float4*)(dst + (size_t)(j0 + r) * H + i0))[q] = v;
    }
}

// ---------------- K2: partial rows/cols, k-split x5 ----------------
// rowsP[ks][n][o][m] = sum_{c,k in ks-range} X[n,c,m,k]*T[o,c,m,k]
// colsP[ks][n][o][m] = sum_{c,k in ks-range} XT[n,c,m,k]*T[o,c,m,k]  (T symmetric)
// grid = 400 m * 5 ksplit = 2000 blocks, 256 threads.
#define KC 40
#define KSPLIT 5
__global__ __launch_bounds__(256) void k_rowscols(const float* __restrict__ x,
        const float* __restrict__ xt, const float* __restrict__ L,
        float* __restrict__ rowsP, float* __restrict__ colsP)
{
    __shared__ __align__(16) float4 Lm[CO * CI];      // L[o,c,m,:]
    __shared__ __align__(16) float Xr[NB * CI * KC];
    __shared__ __align__(16) float Xc[NB * CI * KC];
    __shared__ __align__(16) float Tr[CO * 164];      // o*164 + c*KC + k
    int b = blockIdx.x;
    int m  = b / KSPLIT;
    int ks = b % KSPLIT;
    int tid = threadIdx.x;
    const float4* L4 = (const float4*)L;
    if (tid < CO * CI) Lm[tid] = L4[tid * H + m];

    int o  = tid & 31;
    int n0 = tid >> 5;     // 0..7
    int n1 = n0 + 8;
    float ar0 = 0.f, ar1 = 0.f, ac0 = 0.f, ac1 = 0.f;

    for (int ch = 0; ch < 2; ++ch) {
        int k0 = ks * 80 + ch * KC;
        __syncthreads();
        for (int e = tid; e < NB * CI * KC / 4; e += 256) {   // 640 float4s
            int q  = e % 10;
            int nc = e / 10;
            ((float4*)Xr)[e] = *(const float4*)(x  + (size_t)(nc * H + m) * H + k0 + q * 4);
            ((float4*)Xc)[e] = *(const float4*)(xt + (size_t)(nc * H + m) * H + k0 + q * 4);
        }
        for (int e = tid; e < CO * CI * KC; e += 256) {       // 5120
            int k  = e % KC;
            int oc = e / KC;
            float4 lv = L4[oc * H + k0 + k];
            float4 lm = Lm[oc];
            Tr[(oc >> 2) * 164 + (oc & 3) * KC + k] =
                lv.x * lm.x + lv.y * lm.y + lv.z * lm.z + lv.w * lm.w;
        }
        __syncthreads();
        #pragma unroll
        for (int c = 0; c < CI; ++c) {
            const float4* trp = (const float4*)(Tr + o * 164 + c * KC);
            const float4* pr0 = (const float4*)(Xr + (n0 * CI + c) * KC);
            const float4* pr1 = (const float4*)(Xr + (n1 * CI + c) * KC);
            const float4* pc0 = (const float4*)(Xc + (n0 * CI + c) * KC);
            const float4* pc1 = (const float4*)(Xc + (n1 * CI + c) * KC);
            #pragma unroll
            for (int q = 0; q < KC / 4; ++q) {
                float4 tv = trp[q];
                float4 a  = pr0[q];
                float4 bb = pr1[q];
                float4 cc = pc0[q];
                float4 dd = pc1[q];
                ar0 += tv.x * a.x  + tv.y * a.y  + tv.z * a.z  + tv.w * a.w;
                ar1 += tv.x * bb.x + tv.y * bb.y + tv.z * bb.z + tv.w * bb.w;
                ac0 += tv.x * cc.x + tv.y * cc.y + tv.z * cc.z + tv.w * cc.w;
                ac1 += tv.x * dd.x + tv.y * dd.y + tv.z * dd.z + tv.w * dd.w;
            }
        }
    }
    size_t base = (size_t)ks * NB * CO * H;
    rowsP[base + (size_t)(n0 * CO + o) * H + m] = ar0;
    rowsP[base + (size_t)(n1 * CO + o) * H + m] = ar1;
    colsP[base + (size_t)(n0 * CO + o) * H + m] = ac0;
    colsP[base + (size_t)(n1 * CO + o) * H + m] = ac1;
}

// ---------------- K2b: reduce the 5 partials ----------------
__global__ __launch_bounds__(256) void k_reduce(const float* __restrict__ rowsP,
        const float* __restrict__ colsP, float* __restrict__ rows, float* __restrict__ cols)
{
    int i = blockIdx.x * 256 + threadIdx.x;    // NB*CO*H = 204800 total
    if (i < NB * CO * H) {
        float s = 0.f, t = 0.f;
        #pragma unroll
        for (int k = 0; k < KSPLIT; ++k) {
            s += rowsP[(size_t)k * NB * CO * H + i];
            t += colsP[(size_t)k * NB * CO * H + i];
        }
        rows[i] = s;
        cols[i] = t;
    }
}

// ---------------- K3: final output ----------------
// 16x16 spatial tile; X tile staged ONCE, all 32 o handled via os-loop inside.
// grid = 625 blocks, 512 threads. LDS 80 KB -> 2 blocks/CU.
#define TS 16
__global__ __launch_bounds__(512) void k_out(const float* __restrict__ x,
        const float* __restrict__ L, const float* __restrict__ bias,
        const float* __restrict__ rows, const float* __restrict__ cols,
        float* __restrict__ out)
{
    __shared__ __align__(16) float Xl[NB * CI * TS * TS];  // 64 KB [n][c][ii][jj]
    __shared__ __align__(16) float rT[NB * 8 * TS];        // 8 KB  [n][o][ii]
    __shared__ __align__(16) float cT[NB * 8 * TS];        // 8 KB  [n][o][jj]
    int b = blockIdx.x;
    int ti = b / 25, tj = b % 25;
    int i0 = ti * TS, j0 = tj * TS;
    int tid = threadIdx.x;

    const float4* x4 = (const float4*)x;
    float4* Xl4 = (float4*)Xl;
    for (int e = tid; e < NB * CI * TS * 4; e += 512) {
        int q  = e & 3;
        int ii = (e >> 2) & 15;
        int nc = e >> 6;
        Xl4[e] = x4[(size_t)(nc * H + i0 + ii) * 100 + tj * 4 + q];
    }

    int o  = tid >> 6;             // 0..7
    int u  = tid & 63;
    int ii = u >> 2, jq = u & 3;
    const float4* L4 = (const float4*)L;
    const float4* cT4 = (const float4*)cT;
    float4* out4 = (float4*)out;

    for (int os = 0; os < 4; ++os) {
        int og = os * 8 + o;
        float4 T4[CI];
        #pragma unroll
        for (int c = 0; c < CI; ++c) {
            float4 Li = L4[(og * CI + c) * H + i0 + ii];
            float4 La = L4[(og * CI + c) * H + j0 + jq * 4 + 0];
            float4 Lb = L4[(og * CI + c) * H + j0 + jq * 4 + 1];
            float4 Lc = L4[(og * CI + c) * H + j0 + jq * 4 + 2];
            float4 Ld = L4[(og * CI + c) * H + j0 + jq * 4 + 3];
            T4[c].x = Li.x * La.x + Li.y * La.y + Li.z * La.z + Li.w * La.w;
            T4[c].y = Li.x * Lb.x + Li.y * Lb.y + Li.z * Lb.z + Li.w * Lb.w;
            T4[c].z = Li.x * Lc.x + Li.y * Lc.y + Li.z * Lc.z + Li.w * Lc.w;
            T4[c].w = Li.x * Ld.x + Li.y * Ld.y + Li.z * Ld.z + Li.w * Ld.w;
        }
        float bo = bias[og];

        __syncthreads();   // also covers initial Xl staging (os==0)
        for (int e = tid; e < NB * 8 * TS; e += 512) {
            int iw = e & 15;
            int oo = (e >> 4) & 7;
            int n  = e >> 7;
            rT[e] = rows[(size_t)(n * CO + os * 8 + oo) * H + i0 + iw];
            cT[e] = cols[(size_t)(n * CO + os * 8 + oo) * H + j0 + iw];
        }
        __syncthreads();

        for (int n = 0; n < NB; ++n) {
            float ra = rT[(n * 8 + o) * TS + ii] + bo;
            float4 ca = cT4[(n * 8 + o) * 4 + jq];
            float4 acc;
            acc.x = ra + ca.x; acc.y = ra + ca.y; acc.z = ra + ca.z; acc.w = ra + ca.w;
            #pragma unroll
            for (int c = 0; c < CI; ++c) {
                float4 xv = Xl4[((n * CI + c) * TS + ii) * 4 + jq];
                acc.x -= xv.x * T4[c].x;
                acc.y -= xv.y * T4[c].y;
                acc.z -= xv.z * T4[c].z;
                acc.w -= xv.w * T4[c].w;
            }
            out4[((size_t)(n * CO + og) * H + i0 + ii) * 100 + tj * 4 + jq] = acc;
        }
    }
}

extern "C" void kernel_launch(void* const* d_in, const int* in_sizes, int n_in,
                              void* d_out, int out_size, void* d_ws, size_t ws_size,
                              hipStream_t stream) {
    const float* x    = (const float*)d_in[0];
    const float* L    = (const float*)d_in[1];
    const float* bias = (const float*)d_in[2];
    float* out = (float*)d_out;
    char* ws = (char*)d_ws;

    size_t xt_bytes = (size_t)NB * CI * H * H * sizeof(float);       // 40,960,000
    size_t rc_elems = (size_t)NB * CO * H;                           // 204,800
    size_t rcP_bytes = (size_t)KSPLIT * rc_elems * sizeof(float);    // 4,096,000
    size_t rc_bytes  = rc_elems * sizeof(float);

    float* XT    = (float*)ws;
    float* rowsP = (float*)(ws + xt_bytes);
    float* colsP = (float*)(ws + xt_bytes + rcP_bytes);
    float* rows  = (float*)(ws + xt_bytes + 2 * rcP_bytes);
    float* cols  = (float*)(ws + xt_bytes + 2 * rcP_bytes + rc_bytes);
    (void)ws_size;

    k_transpose<<<1600, 256, 0, stream>>>(x, XT);
    k_rowscols<<<H * KSPLIT, 256, 0, stream>>>(x, XT, L, rowsP, colsP);
    k_reduce<<<(NB * CO * H + 255) / 256, 256, 0, stream>>>(rowsP, colsP, rows, cols);
    k_out<<<625, 512, 0, stream>>>(x, L, bias, rows, cols, out);
}